// Round 4
// baseline (701.094 us; speedup 1.0000x reference)
//
#include <hip/hip_runtime.h>
#include <hip/hip_bf16.h>

#define HN 128
#define EPS 1e-5f
#define BSH 9              // bucket = row >> 9 (512 rows/bucket)
#define BROWS 512
#define NBKT_MAX 256
#define BCAP 32            // staged pairs per bucket in bin_k
#define BTHR 16            // flush threshold

// ---------------- GEMM: m = relu(x @ W^T + b), output bf16 ----------------
__global__ __launch_bounds__(256) void gemm_relu_k(
    const float* __restrict__ x, const float* __restrict__ W,
    const float* __restrict__ bias, __hip_bfloat16* __restrict__ m,
    int nrows) {
  __shared__ float4 Wl[128 * 32];  // 64 KB, swizzled
  __shared__ float4 xl[32 * 32];   // 16 KB, 32 rows
  const int t = threadIdx.x;
  const int o = t & 127;
  const int g = t >> 7;

  for (int f = t; f < 128 * 32; f += 256) {
    const int ro = f >> 5, c = f & 31;
    Wl[ro * 32 + (c ^ (ro & 7))] = reinterpret_cast<const float4*>(W)[f];
  }
  const float bo = bias[o];

  const int r0 = blockIdx.x * 32;
  if (r0 >= nrows) return;
  const int nr = min(32, nrows - r0);

  if (nr == 32) {
    for (int f = t; f < 32 * 32; f += 256)
      xl[f] = reinterpret_cast<const float4*>(x + (size_t)r0 * HN)[f];
  } else {
    for (int f = t; f < 32 * 32; f += 256) {
      const int rr = f >> 5;
      float4 z = {0.f, 0.f, 0.f, 0.f};
      xl[f] = (rr < nr) ? reinterpret_cast<const float4*>(x + (size_t)r0 * HN)[f] : z;
    }
  }
  __syncthreads();

  float acc[16];
#pragma unroll
  for (int r = 0; r < 16; ++r) acc[r] = bo;

  const float4* xg = &xl[(g * 16) * 32];
#pragma unroll 8
  for (int k4 = 0; k4 < 32; ++k4) {
    const float4 wv = Wl[o * 32 + (k4 ^ (o & 7))];
#pragma unroll
    for (int r = 0; r < 16; ++r) {
      const float4 xv = xg[r * 32 + k4];
      acc[r] = fmaf(xv.x, wv.x, acc[r]);
      acc[r] = fmaf(xv.y, wv.y, acc[r]);
      acc[r] = fmaf(xv.z, wv.z, acc[r]);
      acc[r] = fmaf(xv.w, wv.w, acc[r]);
    }
  }

#pragma unroll
  for (int r = 0; r < 16; ++r) {
    const int row = r0 + g * 16 + r;
    if (row < nrows)
      m[(size_t)row * HN + o] = __float2bfloat16(fmaxf(acc[r], 0.f));
  }
}

// ---------------- A1: per-bucket edge counts ----------------
__global__ __launch_bounds__(256) void bcount_k(const int* __restrict__ rows,
                                                int* __restrict__ btotal,
                                                int nedges, int nbkt) {
  __shared__ int h[NBKT_MAX];
  h[threadIdx.x] = 0;
  __syncthreads();
  for (int e = blockIdx.x * blockDim.x + threadIdx.x; e < nedges;
       e += gridDim.x * blockDim.x)
    atomicAdd(&h[rows[e] >> BSH], 1);
  __syncthreads();
  const int b = threadIdx.x;
  if (b < nbkt && h[b]) atomicAdd(&btotal[b], h[b]);
}

// ---------------- A2: scan bucket totals -> base, gcur ----------------
__global__ __launch_bounds__(256) void bscan_k(const int* __restrict__ btotal,
                                               int* __restrict__ base,
                                               int* __restrict__ gcur,
                                               int nbkt, int nedges) {
  __shared__ int s[256];
  const int t = threadIdx.x;
  s[t] = (t < nbkt) ? btotal[t] : 0;
  __syncthreads();
  for (int off = 1; off < 256; off <<= 1) {
    int u = (t >= off) ? s[t - off] : 0;
    __syncthreads();
    if (t >= off) s[t] += u;
    __syncthreads();
  }
  if (t < nbkt) {
    const int e = (t == 0) ? 0 : s[t - 1];
    base[t] = e;
    gcur[t] = e;
  }
  if (t == 0) base[nbkt] = nedges;
}

// ---------------- A3: LDS-staged binning into bucket-sorted pairs ----------
// pair = (row & 511) << 17 | col   (col < 2^17)
__global__ __launch_bounds__(256) void bin_k(const int* __restrict__ rows,
                                             const int* __restrict__ cols,
                                             int* __restrict__ gcur,
                                             unsigned* __restrict__ pairs,
                                             int nedges, int nbkt) {
  __shared__ int cnt[NBKT_MAX];
  __shared__ unsigned bin[NBKT_MAX][BCAP];  // 32 KB
  const int t = threadIdx.x;
  const int wave = t >> 6, lane = t & 63;
  for (int b = t; b < NBKT_MAX; b += 256) cnt[b] = 0;
  __syncthreads();

  const int per = (nedges + gridDim.x - 1) / gridDim.x;
  const int e0 = blockIdx.x * per;
  const int e1 = min(e0 + per, nedges);

  for (int tb = e0; tb < e1; tb += 256) {
    const int e = tb + t;
    if (e < e1) {
      const int r = rows[e];
      const unsigned v = ((unsigned)(r & (BROWS - 1)) << 17) | (unsigned)cols[e];
      const int b = r >> BSH;
      const int p = atomicAdd(&cnt[b], 1);
      if (p < BCAP) {
        bin[b][p] = v;
      } else {  // rare overflow: direct write, undo count
        atomicSub(&cnt[b], 1);
        const int g = atomicAdd(&gcur[b], 1);
        pairs[g] = v;
      }
    }
    __syncthreads();
    // flush bins with cnt >= BTHR (wave w owns buckets b % 4 == w)
    for (int b = wave; b < nbkt; b += 4) {
      const int c = cnt[b];
      if (c >= BTHR) {
        int g;
        if (lane == 0) g = atomicAdd(&gcur[b], c);
        g = __shfl(g, 0);
        if (lane < c) pairs[g + lane] = bin[b][lane];
        if (lane == 0) cnt[b] = 0;
      }
    }
    __syncthreads();
  }
  // final flush
  for (int b = wave; b < nbkt; b += 4) {
    const int c = cnt[b];
    if (c > 0) {
      int g;
      if (lane == 0) g = atomicAdd(&gcur[b], c);
      g = __shfl(g, 0);
      if (lane < c) pairs[g + lane] = bin[b][lane];
    }
  }
}

// ---------------- B: per-bucket rowptr + CSR fill (L2-local scatter) -------
__global__ __launch_bounds__(256) void fillB_k(const unsigned* __restrict__ pairs,
                                               const int* __restrict__ base,
                                               int* __restrict__ rowptr,
                                               int* __restrict__ csr,
                                               int n, int nedges) {
  __shared__ int ldeg[BROWS];
  __shared__ int cur[BROWS];
  __shared__ int s2[256];
  const int b = blockIdx.x;
  const int t = threadIdx.x;
  const int b0 = base[b], b1 = base[b + 1];
  const int lo = b << BSH;
  const int hi = min(lo + BROWS, n);

  ldeg[t] = 0;
  ldeg[t + 256] = 0;
  __syncthreads();
  for (int i = b0 + t; i < b1; i += 256) atomicAdd(&ldeg[pairs[i] >> 17], 1);
  __syncthreads();

  const int a0 = ldeg[2 * t], a1 = ldeg[2 * t + 1];
  s2[t] = a0 + a1;
  __syncthreads();
  for (int off = 1; off < 256; off <<= 1) {
    int u = (t >= off) ? s2[t - off] : 0;
    __syncthreads();
    if (t >= off) s2[t] += u;
    __syncthreads();
  }
  const int ep = (t == 0) ? 0 : s2[t - 1];
  cur[2 * t] = ep;
  cur[2 * t + 1] = ep + a0;
  __syncthreads();

  for (int r = lo + t; r < hi; r += 256) rowptr[r] = b0 + cur[r - lo];
  if (b == 0 && t == 0) rowptr[n] = nedges;
  __syncthreads();

  for (int i = b0 + t; i < b1; i += 256) {
    const unsigned v = pairs[i];
    const int p = atomicAdd(&cur[v >> 17], 1);
    csr[b0 + p] = (int)(v & 0x1FFFFu);
  }
}

// ---------------- gather + avg + residual + RMSNorm (fused) ----------------
__global__ __launch_bounds__(256) void gather_k(
    const __hip_bfloat162* __restrict__ m2, const int* __restrict__ rowptr,
    const int* __restrict__ csr, const float* __restrict__ x,
    const float* __restrict__ gamma, const float* __restrict__ beta,
    float* __restrict__ out, int nrows) {
  const int r = blockIdx.x * 4 + (threadIdx.x >> 6);
  if (r >= nrows) return;
  const int lane = threadIdx.x & 63;

  const int start = rowptr[r];
  const int end = rowptr[r + 1];
  float a0 = 0.f, a1 = 0.f;
  for (int base = start; base < end; base += 64) {
    const int nv = min(64, end - base);
    const int c = (base + lane < end) ? csr[base + lane] : 0;
    for (int j = 0; j < nv; ++j) {
      const int cc = __shfl(c, j);
      const __hip_bfloat162 v = m2[(size_t)cc * 64 + lane];
      a0 += __bfloat162float(v.x);
      a1 += __bfloat162float(v.y);
    }
  }

  const int d = end - start;
  const float inv_d = (d > 0) ? 1.f / (float)d : 1.f;
  const float2 xv = reinterpret_cast<const float2*>(x)[(size_t)r * 64 + lane];
  const float h0 = xv.x + a0 * inv_d;
  const float h1 = xv.y + a1 * inv_d;

  float ss = h0 * h0 + h1 * h1;
#pragma unroll
  for (int off = 1; off < 64; off <<= 1) ss += __shfl_xor(ss, off);
  const float invrms = rsqrtf(ss * (1.f / HN) + EPS);

  const float g0 = gamma[lane * 2], g1 = gamma[lane * 2 + 1];
  const float b0 = beta[lane * 2], b1 = beta[lane * 2 + 1];
  float2 o2;
  o2.x = h0 * invrms * g0 + b0;
  o2.y = h1 * invrms * g1 + b1;
  reinterpret_cast<float2*>(out)[(size_t)r * 64 + lane] = o2;
}

extern "C" void kernel_launch(void* const* d_in, const int* in_sizes, int n_in,
                              void* d_out, int out_size, void* d_ws,
                              size_t ws_size, hipStream_t stream) {
  const float* x = (const float*)d_in[0];
  const float* W = (const float*)d_in[1];
  const float* b = (const float*)d_in[2];
  const float* gamma = (const float*)d_in[3];
  const float* beta = (const float*)d_in[4];
  const int* rows = (const int*)d_in[5];
  const int* cols = (const int*)d_in[6];
  float* out = (float*)d_out;

  const int N = in_sizes[0] / HN;  // 100000
  const int E = in_sizes[5];       // 1600000
  const int nbkt = (N + BROWS - 1) >> BSH;  // 196

  // ws layout: m_bf16 | pairs | csr | rowptr | btotal | base | gcur
  char* p = (char*)d_ws;
  __hip_bfloat16* m = (__hip_bfloat16*)p;
  p += ((size_t)N * HN * sizeof(__hip_bfloat16) + 255) & ~(size_t)255;
  unsigned* pairs = (unsigned*)p;
  p += ((size_t)E * sizeof(unsigned) + 255) & ~(size_t)255;
  int* csr = (int*)p;
  p += ((size_t)E * sizeof(int) + 255) & ~(size_t)255;
  int* rowptr = (int*)p;
  p += ((size_t)(N + 1) * sizeof(int) + 255) & ~(size_t)255;
  int* btotal = (int*)p;
  p += ((size_t)NBKT_MAX * sizeof(int) + 255) & ~(size_t)255;
  int* base = (int*)p;
  p += ((size_t)(NBKT_MAX + 1) * sizeof(int) + 255) & ~(size_t)255;
  int* gcur = (int*)p;

  hipMemsetAsync(btotal, 0, (size_t)NBKT_MAX * sizeof(int), stream);

  const int gemm_blocks = (N + 31) / 32;
  gemm_relu_k<<<gemm_blocks, 256, 0, stream>>>(x, W, b, m, N);
  bcount_k<<<1024, 256, 0, stream>>>(rows, btotal, E, nbkt);
  bscan_k<<<1, 256, 0, stream>>>(btotal, base, gcur, nbkt, E);
  bin_k<<<512, 256, 0, stream>>>(rows, cols, gcur, pairs, E, nbkt);
  fillB_k<<<nbkt, 256, 0, stream>>>(pairs, base, rowptr, csr, N, E);
  gather_k<<<(N + 3) / 4, 256, 0, stream>>>(
      (const __hip_bfloat162*)m, rowptr, csr, x, gamma, beta, out, N);
}

// Round 5
// 693.772 us; speedup vs baseline: 1.0106x; 1.0106x over previous
//
#include <hip/hip_runtime.h>
#include <hip/hip_bf16.h>

#define HN 128
#define EPS 1e-5f
#define SCHUNK 256   // scan elements per block
#define NSLC 64      // row slices for the CSR fill
#define CHMAX 1568   // max rows per slice (ceil(100000/64)=1563)

// ---------------- GEMM: m = relu(x @ W^T + b), output bf16 ----------------
__global__ __launch_bounds__(256) void gemm_relu_k(
    const float* __restrict__ x, const float* __restrict__ W,
    const float* __restrict__ bias, __hip_bfloat16* __restrict__ m,
    int nrows) {
  __shared__ float4 Wl[128 * 32];  // 64 KB, swizzled
  __shared__ float4 xl[32 * 32];   // 16 KB, 32 rows
  const int t = threadIdx.x;
  const int o = t & 127;
  const int g = t >> 7;

  for (int f = t; f < 128 * 32; f += 256) {
    const int ro = f >> 5, c = f & 31;
    Wl[ro * 32 + (c ^ (ro & 7))] = reinterpret_cast<const float4*>(W)[f];
  }
  const float bo = bias[o];

  const int r0 = blockIdx.x * 32;
  if (r0 >= nrows) return;
  const int nr = min(32, nrows - r0);

  if (nr == 32) {
    for (int f = t; f < 32 * 32; f += 256)
      xl[f] = reinterpret_cast<const float4*>(x + (size_t)r0 * HN)[f];
  } else {
    for (int f = t; f < 32 * 32; f += 256) {
      const int rr = f >> 5;
      float4 z = {0.f, 0.f, 0.f, 0.f};
      xl[f] = (rr < nr) ? reinterpret_cast<const float4*>(x + (size_t)r0 * HN)[f] : z;
    }
  }
  __syncthreads();

  float acc[16];
#pragma unroll
  for (int r = 0; r < 16; ++r) acc[r] = bo;

  const float4* xg = &xl[(g * 16) * 32];
#pragma unroll 8
  for (int k4 = 0; k4 < 32; ++k4) {
    const float4 wv = Wl[o * 32 + (k4 ^ (o & 7))];
#pragma unroll
    for (int r = 0; r < 16; ++r) {
      const float4 xv = xg[r * 32 + k4];
      acc[r] = fmaf(xv.x, wv.x, acc[r]);
      acc[r] = fmaf(xv.y, wv.y, acc[r]);
      acc[r] = fmaf(xv.z, wv.z, acc[r]);
      acc[r] = fmaf(xv.w, wv.w, acc[r]);
    }
  }

#pragma unroll
  for (int r = 0; r < 16; ++r) {
    const int row = r0 + g * 16 + r;
    if (row < nrows)
      m[(size_t)row * HN + o] = __float2bfloat16(fmaxf(acc[r], 0.f));
  }
}

// ---------------- degree histogram ----------------
__global__ void degree_k(const int* __restrict__ rows, int* __restrict__ deg,
                         int nedges) {
  for (int e = blockIdx.x * blockDim.x + threadIdx.x; e < nedges;
       e += gridDim.x * blockDim.x)
    atomicAdd(&deg[rows[e]], 1);
}

// ---------------- two-level scan ----------------
__global__ __launch_bounds__(SCHUNK) void blocksum_k(const int* __restrict__ deg,
                                                     int* __restrict__ bsum,
                                                     int n) {
  __shared__ int s[SCHUNK];
  const int i = blockIdx.x * SCHUNK + threadIdx.x;
  int v = (i < n) ? deg[i] : 0;
  s[threadIdx.x] = v;
  __syncthreads();
  for (int off = SCHUNK / 2; off > 0; off >>= 1) {
    if (threadIdx.x < off) s[threadIdx.x] += s[threadIdx.x + off];
    __syncthreads();
  }
  if (threadIdx.x == 0) bsum[blockIdx.x] = s[0];
}

__global__ __launch_bounds__(1024) void scan_bsums_k(int* __restrict__ bsum,
                                                     int* __restrict__ rowptr,
                                                     int nb, int n) {
  __shared__ int s[1024];
  const int t = threadIdx.x;
  int v = (t < nb) ? bsum[t] : 0;
  s[t] = v;
  __syncthreads();
  for (int off = 1; off < 1024; off <<= 1) {
    int u = 0;
    if (t >= off) u = s[t - off];
    __syncthreads();
    if (t >= off) s[t] += u;
    __syncthreads();
  }
  if (t < nb) bsum[t] = (t == 0) ? 0 : s[t - 1];
  if (t == 0) rowptr[n] = s[1023];
}

__global__ __launch_bounds__(SCHUNK) void rowptr_k(const int* __restrict__ deg,
                                                   const int* __restrict__ bsum,
                                                   int* __restrict__ rowptr,
                                                   int n) {
  __shared__ int s[SCHUNK];
  const int i = blockIdx.x * SCHUNK + threadIdx.x;
  const int t = threadIdx.x;
  int v = (i < n) ? deg[i] : 0;
  s[t] = v;
  __syncthreads();
  for (int off = 1; off < SCHUNK; off <<= 1) {
    int u = 0;
    if (t >= off) u = s[t - off];
    __syncthreads();
    if (t >= off) s[t] += u;
    __syncthreads();
  }
  if (i < n) rowptr[i] = bsum[blockIdx.x] + s[t] - v;  // exclusive
}

// ---------------- row-sliced CSR fill ----------------
// Block b owns rows [b*ch, b*ch+ch). It scans the WHOLE rows[] array
// (int4 loads, L3-resident after degree_k) and keeps only its slice's
// edges. Cursors live in LDS (init from rowptr); csr writes land in this
// block's private contiguous span -> each 64B line written by ONE block
// (R3 fill_k: 16 blocks/line -> 105 MB write amplification).
__global__ __launch_bounds__(1024) void fills_k(
    const int* __restrict__ rows, const int* __restrict__ cols,
    const int* __restrict__ rowptr, int* __restrict__ csr, int n, int nedges,
    int ch) {
  __shared__ int cur[CHMAX];
  const int lo = blockIdx.x * ch;
  const int hi = min(lo + ch, n);
  for (int r = lo + threadIdx.x; r < hi; r += 1024) cur[r - lo] = rowptr[r];
  __syncthreads();

  const int4* rows4 = reinterpret_cast<const int4*>(rows);
  const int ne4 = nedges >> 2;
  for (int i = threadIdx.x; i < ne4; i += 1024) {
    const int4 rv = rows4[i];
    const int e = i << 2;
    if (rv.x >= lo && rv.x < hi) csr[atomicAdd(&cur[rv.x - lo], 1)] = cols[e];
    if (rv.y >= lo && rv.y < hi) csr[atomicAdd(&cur[rv.y - lo], 1)] = cols[e + 1];
    if (rv.z >= lo && rv.z < hi) csr[atomicAdd(&cur[rv.z - lo], 1)] = cols[e + 2];
    if (rv.w >= lo && rv.w < hi) csr[atomicAdd(&cur[rv.w - lo], 1)] = cols[e + 3];
  }
  for (int e = (ne4 << 2) + threadIdx.x; e < nedges; e += 1024) {
    const int r = rows[e];
    if (r >= lo && r < hi) csr[atomicAdd(&cur[r - lo], 1)] = cols[e];
  }
}

// ---------------- gather + avg + residual + RMSNorm (fused) ----------------
__global__ __launch_bounds__(256) void gather_k(
    const __hip_bfloat162* __restrict__ m2, const int* __restrict__ rowptr,
    const int* __restrict__ csr, const float* __restrict__ x,
    const float* __restrict__ gamma, const float* __restrict__ beta,
    float* __restrict__ out, int nrows) {
  const int r = blockIdx.x * 4 + (threadIdx.x >> 6);
  if (r >= nrows) return;
  const int lane = threadIdx.x & 63;

  const int start = rowptr[r];
  const int end = rowptr[r + 1];
  float a0 = 0.f, a1 = 0.f;
  for (int base = start; base < end; base += 64) {
    const int nv = min(64, end - base);
    const int c = (base + lane < end) ? csr[base + lane] : 0;
    for (int j = 0; j < nv; ++j) {
      const int cc = __shfl(c, j);
      const __hip_bfloat162 v = m2[(size_t)cc * 64 + lane];
      a0 += __bfloat162float(v.x);
      a1 += __bfloat162float(v.y);
    }
  }

  const int d = end - start;
  const float inv_d = (d > 0) ? 1.f / (float)d : 1.f;
  const float2 xv = reinterpret_cast<const float2*>(x)[(size_t)r * 64 + lane];
  const float h0 = xv.x + a0 * inv_d;
  const float h1 = xv.y + a1 * inv_d;

  float ss = h0 * h0 + h1 * h1;
#pragma unroll
  for (int off = 1; off < 64; off <<= 1) ss += __shfl_xor(ss, off);
  const float invrms = rsqrtf(ss * (1.f / HN) + EPS);

  const float g0 = gamma[lane * 2], g1 = gamma[lane * 2 + 1];
  const float b0 = beta[lane * 2], b1 = beta[lane * 2 + 1];
  float2 o2;
  o2.x = h0 * invrms * g0 + b0;
  o2.y = h1 * invrms * g1 + b1;
  reinterpret_cast<float2*>(out)[(size_t)r * 64 + lane] = o2;
}

extern "C" void kernel_launch(void* const* d_in, const int* in_sizes, int n_in,
                              void* d_out, int out_size, void* d_ws,
                              size_t ws_size, hipStream_t stream) {
  const float* x = (const float*)d_in[0];
  const float* W = (const float*)d_in[1];
  const float* b = (const float*)d_in[2];
  const float* gamma = (const float*)d_in[3];
  const float* beta = (const float*)d_in[4];
  const int* rows = (const int*)d_in[5];
  const int* cols = (const int*)d_in[6];
  float* out = (float*)d_out;

  const int N = in_sizes[0] / HN;  // 100000
  const int E = in_sizes[5];       // 1600000

  // ws layout: m_bf16 | deg | rowptr | bsum | csr
  char* p = (char*)d_ws;
  __hip_bfloat16* m = (__hip_bfloat16*)p;
  p += ((size_t)N * HN * sizeof(__hip_bfloat16) + 255) & ~(size_t)255;
  int* deg = (int*)p;
  p += ((size_t)N * sizeof(int) + 255) & ~(size_t)255;
  int* rowptr = (int*)p;
  p += ((size_t)(N + 1) * sizeof(int) + 255) & ~(size_t)255;
  int* bsum = (int*)p;
  p += ((size_t)2048 * sizeof(int) + 255) & ~(size_t)255;
  int* csr = (int*)p;

  hipMemsetAsync(deg, 0, (size_t)N * sizeof(int), stream);

  const int nb = (N + SCHUNK - 1) / SCHUNK;  // 391
  const int ch = (N + NSLC - 1) / NSLC;      // 1563
  const int gemm_blocks = (N + 31) / 32;

  gemm_relu_k<<<gemm_blocks, 256, 0, stream>>>(x, W, b, m, N);
  degree_k<<<1024, 256, 0, stream>>>(rows, deg, E);
  blocksum_k<<<nb, SCHUNK, 0, stream>>>(deg, bsum, N);
  scan_bsums_k<<<1, 1024, 0, stream>>>(bsum, rowptr, nb, N);
  rowptr_k<<<nb, SCHUNK, 0, stream>>>(deg, bsum, rowptr, N);
  fills_k<<<NSLC, 1024, 0, stream>>>(rows, cols, rowptr, csr, N, E, ch);
  gather_k<<<(N + 3) / 4, 256, 0, stream>>>(
      (const __hip_bfloat162*)m, rowptr, csr, x, gamma, beta, out, N);
}

// Round 6
// 314.583 us; speedup vs baseline: 2.2286x; 2.2054x over previous
//
#include <hip/hip_runtime.h>
#include <hip/hip_bf16.h>

#define HN 128
#define EPS 1e-5f
#define SCHUNK 256   // scan elements per block
#define NSLC 64      // row slices for the CSR fill
#define NSUB 8       // edge sub-ranges per slice

typedef __attribute__((ext_vector_type(8))) short bf16x8;
typedef __attribute__((ext_vector_type(4))) float f32x4;

static __device__ inline short f2bs(float f) {
  __hip_bfloat16 h = __float2bfloat16(f);
  return *reinterpret_cast<short*>(&h);
}

// ---------------- W f32 -> bf16 ----------------
__global__ __launch_bounds__(256) void wconv_k(const float* __restrict__ W,
                                               __hip_bfloat16* __restrict__ Wbf) {
  const int i = blockIdx.x * 256 + threadIdx.x;
  if (i < HN * HN) Wbf[i] = __float2bfloat16(W[i]);
}

// ---------------- GEMM via MFMA: m = relu(x @ W^T + b), bf16 out ----------
// Block = 256 (4 waves), each wave owns a 16-row tile (nrows % 16 == 0).
// B-fragments (all of W^T) live in registers: 8 N-tiles x 4 K-steps x 4 VGPR.
// A-fragments loaded from global f32, converted to bf16 in-register. No LDS.
// Layouts (cdna4 guide §3): A/B lane = 16*kg + r, 8 contiguous k;
// C/D col = lane&15, row = (lane>>4)*4 + reg.
__global__ __launch_bounds__(256) void gemm_mfma_k(
    const float* __restrict__ x, const __hip_bfloat16* __restrict__ Wbf,
    const float* __restrict__ bias, __hip_bfloat16* __restrict__ m,
    int nrows) {
  const int lane = threadIdx.x & 63;
  const int wv = threadIdx.x >> 6;
  const int r = lane & 15;
  const int kg = lane >> 4;

  const int row0 = blockIdx.x * 64 + wv * 16;
  if (row0 >= nrows) return;  // 16-row tiles are all-or-nothing (nrows%16==0)

  // B fragments: Bf[n][ks] = W[n*16 + r][ks*32 + kg*8 .. +7]
  bf16x8 Bf[8][4];
#pragma unroll
  for (int n = 0; n < 8; ++n)
#pragma unroll
    for (int ks = 0; ks < 4; ++ks)
      Bf[n][ks] = *reinterpret_cast<const bf16x8*>(
          Wbf + (size_t)(n * 16 + r) * HN + ks * 32 + kg * 8);

  f32x4 acc[8];
#pragma unroll
  for (int n = 0; n < 8; ++n) {
    const float bv = bias[n * 16 + r];
    acc[n] = (f32x4){bv, bv, bv, bv};
  }

  // A fragments: x[row0 + r][ks*32 + kg*8 .. +7], f32 -> bf16
  bf16x8 Af[4];
  const float* xr = x + (size_t)(row0 + r) * HN + kg * 8;
#pragma unroll
  for (int ks = 0; ks < 4; ++ks) {
    const float4 f0 = *reinterpret_cast<const float4*>(xr + ks * 32);
    const float4 f1 = *reinterpret_cast<const float4*>(xr + ks * 32 + 4);
    bf16x8 a;
    a[0] = f2bs(f0.x); a[1] = f2bs(f0.y); a[2] = f2bs(f0.z); a[3] = f2bs(f0.w);
    a[4] = f2bs(f1.x); a[5] = f2bs(f1.y); a[6] = f2bs(f1.z); a[7] = f2bs(f1.w);
    Af[ks] = a;
  }

#pragma unroll
  for (int ks = 0; ks < 4; ++ks)
#pragma unroll
    for (int n = 0; n < 8; ++n)
      acc[n] = __builtin_amdgcn_mfma_f32_16x16x32_bf16(Af[ks], Bf[n][ks],
                                                       acc[n], 0, 0, 0);

  // store: D[row=(kg*4+reg)][col=n*16+r]
#pragma unroll
  for (int n = 0; n < 8; ++n) {
#pragma unroll
    for (int reg = 0; reg < 4; ++reg) {
      const int rr = row0 + kg * 4 + reg;
      m[(size_t)rr * HN + n * 16 + r] =
          __float2bfloat16(fmaxf(acc[n][reg], 0.f));
    }
  }
}

// ---------------- degree histogram ----------------
__global__ void degree_k(const int* __restrict__ rows, int* __restrict__ deg,
                         int nedges) {
  for (int e = blockIdx.x * blockDim.x + threadIdx.x; e < nedges;
       e += gridDim.x * blockDim.x)
    atomicAdd(&deg[rows[e]], 1);
}

// ---------------- two-level scan ----------------
__global__ __launch_bounds__(SCHUNK) void blocksum_k(const int* __restrict__ deg,
                                                     int* __restrict__ bsum,
                                                     int n) {
  __shared__ int s[SCHUNK];
  const int i = blockIdx.x * SCHUNK + threadIdx.x;
  int v = (i < n) ? deg[i] : 0;
  s[threadIdx.x] = v;
  __syncthreads();
  for (int off = SCHUNK / 2; off > 0; off >>= 1) {
    if (threadIdx.x < off) s[threadIdx.x] += s[threadIdx.x + off];
    __syncthreads();
  }
  if (threadIdx.x == 0) bsum[blockIdx.x] = s[0];
}

__global__ __launch_bounds__(1024) void scan_bsums_k(int* __restrict__ bsum,
                                                     int* __restrict__ rowptr,
                                                     int nb, int n) {
  __shared__ int s[1024];
  const int t = threadIdx.x;
  int v = (t < nb) ? bsum[t] : 0;
  s[t] = v;
  __syncthreads();
  for (int off = 1; off < 1024; off <<= 1) {
    int u = 0;
    if (t >= off) u = s[t - off];
    __syncthreads();
    if (t >= off) s[t] += u;
    __syncthreads();
  }
  if (t < nb) bsum[t] = (t == 0) ? 0 : s[t - 1];
  if (t == 0) rowptr[n] = s[1023];
}

__global__ __launch_bounds__(SCHUNK) void rowptr_k(const int* __restrict__ deg,
                                                   const int* __restrict__ bsum,
                                                   int* __restrict__ rowptr,
                                                   int* __restrict__ cursor,
                                                   int n) {
  __shared__ int s[SCHUNK];
  const int i = blockIdx.x * SCHUNK + threadIdx.x;
  const int t = threadIdx.x;
  int v = (i < n) ? deg[i] : 0;
  s[t] = v;
  __syncthreads();
  for (int off = 1; off < SCHUNK; off <<= 1) {
    int u = 0;
    if (t >= off) u = s[t - off];
    __syncthreads();
    if (t >= off) s[t] += u;
    __syncthreads();
  }
  if (i < n) {
    const int excl = bsum[blockIdx.x] + s[t] - v;
    rowptr[i] = excl;
    cursor[i] = excl;
  }
}

// ---------------- row-sliced CSR fill, (slice, subrange) grid -------------
// 512 blocks = 64 slices x 8 edge sub-ranges. Blocks of one slice are
// b === s (mod 8) -> same XCD under round-robin dispatch, so the slice's
// csr span stays L2-local despite 8 writers. Cursors are global atomics.
__global__ __launch_bounds__(1024) void fills_k(
    const int* __restrict__ rows, const int* __restrict__ cols,
    int* __restrict__ cursor, int* __restrict__ csr, int n, int nedges,
    int ch) {
  const int s = blockIdx.x & (NSLC - 1);
  const int sub = blockIdx.x / NSLC;
  const int lo = s * ch;
  const int hi = min(lo + ch, n);
  const int chunk = ((nedges + NSUB - 1) / NSUB + 3) & ~3;
  const int e0 = sub * chunk;
  const int e1 = min(e0 + chunk, nedges);
  if (e0 >= e1) return;

  const int4* rows4 = reinterpret_cast<const int4*>(rows + e0);
  const int nE = e1 - e0;
  const int ne4 = nE >> 2;
  for (int i = threadIdx.x; i < ne4; i += 1024) {
    const int4 rv = rows4[i];
    const int e = e0 + (i << 2);
    if (rv.x >= lo && rv.x < hi) csr[atomicAdd(&cursor[rv.x], 1)] = cols[e];
    if (rv.y >= lo && rv.y < hi) csr[atomicAdd(&cursor[rv.y], 1)] = cols[e + 1];
    if (rv.z >= lo && rv.z < hi) csr[atomicAdd(&cursor[rv.z], 1)] = cols[e + 2];
    if (rv.w >= lo && rv.w < hi) csr[atomicAdd(&cursor[rv.w], 1)] = cols[e + 3];
  }
  for (int e = e0 + (ne4 << 2) + threadIdx.x; e < e1; e += 1024) {
    const int r = rows[e];
    if (r >= lo && r < hi) csr[atomicAdd(&cursor[r], 1)] = cols[e];
  }
}

// ---------------- gather + avg + residual + RMSNorm (fused) ----------------
__global__ __launch_bounds__(256) void gather_k(
    const __hip_bfloat162* __restrict__ m2, const int* __restrict__ rowptr,
    const int* __restrict__ csr, const float* __restrict__ x,
    const float* __restrict__ gamma, const float* __restrict__ beta,
    float* __restrict__ out, int nrows) {
  const int r = blockIdx.x * 4 + (threadIdx.x >> 6);
  if (r >= nrows) return;
  const int lane = threadIdx.x & 63;

  const int start = rowptr[r];
  const int end = rowptr[r + 1];
  float a0 = 0.f, a1 = 0.f;
  for (int base = start; base < end; base += 64) {
    const int nv = min(64, end - base);
    const int c = (base + lane < end) ? csr[base + lane] : 0;
    for (int j = 0; j < nv; ++j) {
      const int cc = __shfl(c, j);
      const __hip_bfloat162 v = m2[(size_t)cc * 64 + lane];
      a0 += __bfloat162float(v.x);
      a1 += __bfloat162float(v.y);
    }
  }

  const int d = end - start;
  const float inv_d = (d > 0) ? 1.f / (float)d : 1.f;
  const float2 xv = reinterpret_cast<const float2*>(x)[(size_t)r * 64 + lane];
  const float h0 = xv.x + a0 * inv_d;
  const float h1 = xv.y + a1 * inv_d;

  float ss = h0 * h0 + h1 * h1;
#pragma unroll
  for (int off = 1; off < 64; off <<= 1) ss += __shfl_xor(ss, off);
  const float invrms = rsqrtf(ss * (1.f / HN) + EPS);

  const float g0 = gamma[lane * 2], g1 = gamma[lane * 2 + 1];
  const float b0 = beta[lane * 2], b1 = beta[lane * 2 + 1];
  float2 o2;
  o2.x = h0 * invrms * g0 + b0;
  o2.y = h1 * invrms * g1 + b1;
  reinterpret_cast<float2*>(out)[(size_t)r * 64 + lane] = o2;
}

extern "C" void kernel_launch(void* const* d_in, const int* in_sizes, int n_in,
                              void* d_out, int out_size, void* d_ws,
                              size_t ws_size, hipStream_t stream) {
  const float* x = (const float*)d_in[0];
  const float* W = (const float*)d_in[1];
  const float* b = (const float*)d_in[2];
  const float* gamma = (const float*)d_in[3];
  const float* beta = (const float*)d_in[4];
  const int* rows = (const int*)d_in[5];
  const int* cols = (const int*)d_in[6];
  float* out = (float*)d_out;

  const int N = in_sizes[0] / HN;  // 100000
  const int E = in_sizes[5];       // 1600000

  // ws layout: m_bf16 | Wbf | deg | rowptr | cursor | bsum | csr
  char* p = (char*)d_ws;
  __hip_bfloat16* m = (__hip_bfloat16*)p;
  p += ((size_t)N * HN * sizeof(__hip_bfloat16) + 255) & ~(size_t)255;
  __hip_bfloat16* Wbf = (__hip_bfloat16*)p;
  p += ((size_t)HN * HN * sizeof(__hip_bfloat16) + 255) & ~(size_t)255;
  int* deg = (int*)p;
  p += ((size_t)N * sizeof(int) + 255) & ~(size_t)255;
  int* rowptr = (int*)p;
  p += ((size_t)(N + 1) * sizeof(int) + 255) & ~(size_t)255;
  int* cursor = (int*)p;
  p += ((size_t)N * sizeof(int) + 255) & ~(size_t)255;
  int* bsum = (int*)p;
  p += ((size_t)2048 * sizeof(int) + 255) & ~(size_t)255;
  int* csr = (int*)p;

  hipMemsetAsync(deg, 0, (size_t)N * sizeof(int), stream);

  const int nb = (N + SCHUNK - 1) / SCHUNK;  // 391
  const int ch = (N + NSLC - 1) / NSLC;      // 1563

  wconv_k<<<(HN * HN + 255) / 256, 256, 0, stream>>>(W, Wbf);
  gemm_mfma_k<<<(N + 63) / 64, 256, 0, stream>>>(x, Wbf, b, m, N);
  degree_k<<<1024, 256, 0, stream>>>(rows, deg, E);
  blocksum_k<<<nb, SCHUNK, 0, stream>>>(deg, bsum, N);
  scan_bsums_k<<<1, 1024, 0, stream>>>(bsum, rowptr, nb, N);
  rowptr_k<<<nb, SCHUNK, 0, stream>>>(deg, bsum, rowptr, cursor, N);
  fills_k<<<NSLC * NSUB, 1024, 0, stream>>>(rows, cols, cursor, csr, N, E, ch);
  gather_k<<<(N + 3) / 4, 256, 0, stream>>>(
      (const __hip_bfloat162*)m, rowptr, csr, x, gamma, beta, out, N);
}

// Round 7
// 267.392 us; speedup vs baseline: 2.6220x; 1.1765x over previous
//
#include <hip/hip_runtime.h>
#include <hip/hip_bf16.h>

#define HN 128
#define EPS 1e-5f
#define SCHUNK 256   // scan elements per block
#define NSLC 8       // row slices for the CSR fill (must divide by 8 for XCD-mod)
#define NSUB 32      // edge sub-ranges per slice

typedef __attribute__((ext_vector_type(8))) short bf16x8;
typedef __attribute__((ext_vector_type(4))) float f32x4;

static __device__ inline short f2bs(float f) {
  __hip_bfloat16 h = __float2bfloat16(f);
  return *reinterpret_cast<short*>(&h);
}

static __device__ inline unsigned char f2fp8(float f) {
  // e4m3 via HW packed convert; take low byte
  unsigned p = __builtin_amdgcn_cvt_pk_fp8_f32(f, f, 0u, false);
  return (unsigned char)(p & 0xffu);
}

// ---------------- W f32 -> bf16 ----------------
__global__ __launch_bounds__(256) void wconv_k(const float* __restrict__ W,
                                               __hip_bfloat16* __restrict__ Wbf) {
  const int i = blockIdx.x * 256 + threadIdx.x;
  if (i < HN * HN) Wbf[i] = __float2bfloat16(W[i]);
}

// ---------------- GEMM via MFMA: m = relu(x @ W^T + b), fp8 out ----------
__global__ __launch_bounds__(256) void gemm_mfma_k(
    const float* __restrict__ x, const __hip_bfloat16* __restrict__ Wbf,
    const float* __restrict__ bias, unsigned char* __restrict__ m8,
    int nrows) {
  const int lane = threadIdx.x & 63;
  const int wv = threadIdx.x >> 6;
  const int r = lane & 15;
  const int kg = lane >> 4;

  const int row0 = blockIdx.x * 64 + wv * 16;
  if (row0 >= nrows) return;  // nrows % 16 == 0

  bf16x8 Bf[8][4];
#pragma unroll
  for (int n = 0; n < 8; ++n)
#pragma unroll
    for (int ks = 0; ks < 4; ++ks)
      Bf[n][ks] = *reinterpret_cast<const bf16x8*>(
          Wbf + (size_t)(n * 16 + r) * HN + ks * 32 + kg * 8);

  f32x4 acc[8];
#pragma unroll
  for (int n = 0; n < 8; ++n) {
    const float bv = bias[n * 16 + r];
    acc[n] = (f32x4){bv, bv, bv, bv};
  }

  bf16x8 Af[4];
  const float* xr = x + (size_t)(row0 + r) * HN + kg * 8;
#pragma unroll
  for (int ks = 0; ks < 4; ++ks) {
    const float4 f0 = *reinterpret_cast<const float4*>(xr + ks * 32);
    const float4 f1 = *reinterpret_cast<const float4*>(xr + ks * 32 + 4);
    bf16x8 a;
    a[0] = f2bs(f0.x); a[1] = f2bs(f0.y); a[2] = f2bs(f0.z); a[3] = f2bs(f0.w);
    a[4] = f2bs(f1.x); a[5] = f2bs(f1.y); a[6] = f2bs(f1.z); a[7] = f2bs(f1.w);
    Af[ks] = a;
  }

#pragma unroll
  for (int ks = 0; ks < 4; ++ks)
#pragma unroll
    for (int n = 0; n < 8; ++n)
      acc[n] = __builtin_amdgcn_mfma_f32_16x16x32_bf16(Af[ks], Bf[n][ks],
                                                       acc[n], 0, 0, 0);

  // D[row=(kg*4+reg)][col=n*16+r] -> fp8 byte store
#pragma unroll
  for (int n = 0; n < 8; ++n) {
#pragma unroll
    for (int reg = 0; reg < 4; ++reg) {
      const int rr = row0 + kg * 4 + reg;
      m8[(size_t)rr * HN + n * 16 + r] = f2fp8(fmaxf(acc[n][reg], 0.f));
    }
  }
}

// ---------------- degree histogram ----------------
__global__ void degree_k(const int* __restrict__ rows, int* __restrict__ deg,
                         int nedges) {
  for (int e = blockIdx.x * blockDim.x + threadIdx.x; e < nedges;
       e += gridDim.x * blockDim.x)
    atomicAdd(&deg[rows[e]], 1);
}

// ---------------- two-level scan ----------------
__global__ __launch_bounds__(SCHUNK) void blocksum_k(const int* __restrict__ deg,
                                                     int* __restrict__ bsum,
                                                     int n) {
  __shared__ int s[SCHUNK];
  const int i = blockIdx.x * SCHUNK + threadIdx.x;
  int v = (i < n) ? deg[i] : 0;
  s[threadIdx.x] = v;
  __syncthreads();
  for (int off = SCHUNK / 2; off > 0; off >>= 1) {
    if (threadIdx.x < off) s[threadIdx.x] += s[threadIdx.x + off];
    __syncthreads();
  }
  if (threadIdx.x == 0) bsum[blockIdx.x] = s[0];
}

__global__ __launch_bounds__(1024) void scan_bsums_k(int* __restrict__ bsum,
                                                     int* __restrict__ rowptr,
                                                     int nb, int n) {
  __shared__ int s[1024];
  const int t = threadIdx.x;
  int v = (t < nb) ? bsum[t] : 0;
  s[t] = v;
  __syncthreads();
  for (int off = 1; off < 1024; off <<= 1) {
    int u = 0;
    if (t >= off) u = s[t - off];
    __syncthreads();
    if (t >= off) s[t] += u;
    __syncthreads();
  }
  if (t < nb) bsum[t] = (t == 0) ? 0 : s[t - 1];
  if (t == 0) rowptr[n] = s[1023];
}

__global__ __launch_bounds__(SCHUNK) void rowptr_k(const int* __restrict__ deg,
                                                   const int* __restrict__ bsum,
                                                   int* __restrict__ rowptr,
                                                   int* __restrict__ cursor,
                                                   int n) {
  __shared__ int s[SCHUNK];
  const int i = blockIdx.x * SCHUNK + threadIdx.x;
  const int t = threadIdx.x;
  int v = (i < n) ? deg[i] : 0;
  s[t] = v;
  __syncthreads();
  for (int off = 1; off < SCHUNK; off <<= 1) {
    int u = 0;
    if (t >= off) u = s[t - off];
    __syncthreads();
    if (t >= off) s[t] += u;
    __syncthreads();
  }
  if (i < n) {
    const int excl = bsum[blockIdx.x] + s[t] - v;
    rowptr[i] = excl;
    cursor[i] = excl;
  }
}

// ---------------- row-sliced CSR fill, (slice, subrange) grid -------------
// 256 blocks = 8 slices x 32 edge sub-ranges. Blocks of one slice are
// b === s (mod 8) -> same XCD under round-robin dispatch -> slice's csr
// span stays L2-local. NSLC=8 cuts redundant rows[] reads 64x -> 8x.
__global__ __launch_bounds__(1024) void fills_k(
    const int* __restrict__ rows, const int* __restrict__ cols,
    int* __restrict__ cursor, int* __restrict__ csr, int n, int nedges,
    int ch) {
  const int s = blockIdx.x & (NSLC - 1);
  const int sub = blockIdx.x / NSLC;
  const int lo = s * ch;
  const int hi = min(lo + ch, n);
  const int chunk = ((nedges + NSUB - 1) / NSUB + 3) & ~3;
  const int e0 = sub * chunk;
  const int e1 = min(e0 + chunk, nedges);
  if (e0 >= e1) return;

  const int4* rows4 = reinterpret_cast<const int4*>(rows + e0);
  const int nE = e1 - e0;
  const int ne4 = nE >> 2;
  for (int i = threadIdx.x; i < ne4; i += 1024) {
    const int4 rv = rows4[i];
    const int e = e0 + (i << 2);
    if (rv.x >= lo && rv.x < hi) csr[atomicAdd(&cursor[rv.x], 1)] = cols[e];
    if (rv.y >= lo && rv.y < hi) csr[atomicAdd(&cursor[rv.y], 1)] = cols[e + 1];
    if (rv.z >= lo && rv.z < hi) csr[atomicAdd(&cursor[rv.z], 1)] = cols[e + 2];
    if (rv.w >= lo && rv.w < hi) csr[atomicAdd(&cursor[rv.w], 1)] = cols[e + 3];
  }
  for (int e = e0 + (ne4 << 2) + threadIdx.x; e < e1; e += 1024) {
    const int r = rows[e];
    if (r >= lo && r < hi) csr[atomicAdd(&cursor[r], 1)] = cols[e];
  }
}

// ---------------- gather + avg + residual + RMSNorm (fused) ----------------
// One wave per row. Half-wave per edge: lanes 0-31 -> edge j, 32-63 -> j+1.
// Lane owns 4 output cols (4*l..4*l+3); per edge-visit it loads uchar4 of
// fp8 m (32 lanes x 4B = 128 B row). shfl_xor(32) combines the halves.
__global__ __launch_bounds__(256) void gather_k(
    const unsigned char* __restrict__ m8, const int* __restrict__ rowptr,
    const int* __restrict__ csr, const float* __restrict__ x,
    const float* __restrict__ gamma, const float* __restrict__ beta,
    float* __restrict__ out, int nrows) {
  const int r = blockIdx.x * 4 + (threadIdx.x >> 6);
  if (r >= nrows) return;
  const int lane = threadIdx.x & 63;
  const int half = lane >> 5;
  const int l = lane & 31;

  const int start = rowptr[r];
  const int end = rowptr[r + 1];
  float a0 = 0.f, a1 = 0.f, a2 = 0.f, a3 = 0.f;
  for (int base = start; base < end; base += 64) {
    const int nv = min(64, end - base);
    const int c = (base + lane < end) ? csr[base + lane] : 0;
    for (int j = 0; j < nv; j += 2) {
      const int cc0 = __shfl(c, j);
      const int cc1 = __shfl(c, j + 1);  // j+1 <= 63, safe lane idx
      const int cc = half ? cc1 : cc0;
      if (half == 0 || j + 1 < nv) {
        const unsigned u =
            *reinterpret_cast<const unsigned*>(m8 + (size_t)cc * HN + 4 * l);
        a0 += __builtin_amdgcn_cvt_f32_fp8(u, 0);
        a1 += __builtin_amdgcn_cvt_f32_fp8(u, 1);
        a2 += __builtin_amdgcn_cvt_f32_fp8(u, 2);
        a3 += __builtin_amdgcn_cvt_f32_fp8(u, 3);
      }
    }
  }
  // combine the two halves (both halves end with identical sums)
  a0 += __shfl_xor(a0, 32);
  a1 += __shfl_xor(a1, 32);
  a2 += __shfl_xor(a2, 32);
  a3 += __shfl_xor(a3, 32);

  const int d = end - start;
  const float inv_d = (d > 0) ? 1.f / (float)d : 1.f;
  const float4 xv = *reinterpret_cast<const float4*>(x + (size_t)r * HN + 4 * l);
  const float h0 = xv.x + a0 * inv_d;
  const float h1 = xv.y + a1 * inv_d;
  const float h2 = xv.z + a2 * inv_d;
  const float h3 = xv.w + a3 * inv_d;

  float ss = h0 * h0 + h1 * h1 + h2 * h2 + h3 * h3;
#pragma unroll
  for (int off = 1; off < 32; off <<= 1) ss += __shfl_xor(ss, off);
  const float invrms = rsqrtf(ss * (1.f / HN) + EPS);

  if (half == 0) {
    const float4 gv = *reinterpret_cast<const float4*>(gamma + 4 * l);
    const float4 bv = *reinterpret_cast<const float4*>(beta + 4 * l);
    float4 o4;
    o4.x = h0 * invrms * gv.x + bv.x;
    o4.y = h1 * invrms * gv.y + bv.y;
    o4.z = h2 * invrms * gv.z + bv.z;
    o4.w = h3 * invrms * gv.w + bv.w;
    *reinterpret_cast<float4*>(out + (size_t)r * HN + 4 * l) = o4;
  }
}

extern "C" void kernel_launch(void* const* d_in, const int* in_sizes, int n_in,
                              void* d_out, int out_size, void* d_ws,
                              size_t ws_size, hipStream_t stream) {
  const float* x = (const float*)d_in[0];
  const float* W = (const float*)d_in[1];
  const float* b = (const float*)d_in[2];
  const float* gamma = (const float*)d_in[3];
  const float* beta = (const float*)d_in[4];
  const int* rows = (const int*)d_in[5];
  const int* cols = (const int*)d_in[6];
  float* out = (float*)d_out;

  const int N = in_sizes[0] / HN;  // 100000
  const int E = in_sizes[5];       // 1600000

  // ws layout: m_fp8 | Wbf | deg | rowptr | cursor | bsum | csr
  char* p = (char*)d_ws;
  unsigned char* m8 = (unsigned char*)p;
  p += ((size_t)N * HN + 255) & ~(size_t)255;
  __hip_bfloat16* Wbf = (__hip_bfloat16*)p;
  p += ((size_t)HN * HN * sizeof(__hip_bfloat16) + 255) & ~(size_t)255;
  int* deg = (int*)p;
  p += ((size_t)N * sizeof(int) + 255) & ~(size_t)255;
  int* rowptr = (int*)p;
  p += ((size_t)(N + 1) * sizeof(int) + 255) & ~(size_t)255;
  int* cursor = (int*)p;
  p += ((size_t)N * sizeof(int) + 255) & ~(size_t)255;
  int* bsum = (int*)p;
  p += ((size_t)2048 * sizeof(int) + 255) & ~(size_t)255;
  int* csr = (int*)p;

  hipMemsetAsync(deg, 0, (size_t)N * sizeof(int), stream);

  const int nb = (N + SCHUNK - 1) / SCHUNK;  // 391
  const int ch = (N + NSLC - 1) / NSLC;      // 12500

  wconv_k<<<(HN * HN + 255) / 256, 256, 0, stream>>>(W, Wbf);
  gemm_mfma_k<<<(N + 63) / 64, 256, 0, stream>>>(x, Wbf, b, m8, N);
  degree_k<<<1024, 256, 0, stream>>>(rows, deg, E);
  blocksum_k<<<nb, SCHUNK, 0, stream>>>(deg, bsum, N);
  scan_bsums_k<<<1, 1024, 0, stream>>>(bsum, rowptr, nb, N);
  rowptr_k<<<nb, SCHUNK, 0, stream>>>(deg, bsum, rowptr, cursor, N);
  fills_k<<<NSLC * NSUB, 1024, 0, stream>>>(rows, cols, cursor, csr, N, E, ch);
  gather_k<<<(N + 3) / 4, 256, 0, stream>>>(m8, rowptr, csr, x, gamma, beta,
                                            out, N);
}

// Round 8
// 251.531 us; speedup vs baseline: 2.7873x; 1.0631x over previous
//
#include <hip/hip_runtime.h>
#include <hip/hip_bf16.h>

#define HN 128
#define EPS 1e-5f
#define SCHUNK 256   // scan elements per block
#define NSLC 8       // row slices for the CSR fill (8 -> XCD-mod locality)
#define NSUB 32      // edge sub-ranges per slice

typedef __attribute__((ext_vector_type(8))) short bf16x8;
typedef __attribute__((ext_vector_type(4))) float f32x4;
typedef __attribute__((ext_vector_type(2))) float f32x2;

static __device__ inline short f2bs(float f) {
  __hip_bfloat16 h = __float2bfloat16(f);
  return *reinterpret_cast<short*>(&h);
}

static __device__ inline unsigned char f2fp8(float f) {
  unsigned p = __builtin_amdgcn_cvt_pk_fp8_f32(f, f, 0u, false);
  return (unsigned char)(p & 0xffu);
}

// ---------------- W f32 -> bf16 ----------------
__global__ __launch_bounds__(256) void wconv_k(const float* __restrict__ W,
                                               __hip_bfloat16* __restrict__ Wbf) {
  const int i = blockIdx.x * 256 + threadIdx.x;
  if (i < HN * HN) Wbf[i] = __float2bfloat16(W[i]);
}

// ---------------- GEMM via MFMA: m = relu(x @ W^T + b), fp8 out ----------
__global__ __launch_bounds__(256) void gemm_mfma_k(
    const float* __restrict__ x, const __hip_bfloat16* __restrict__ Wbf,
    const float* __restrict__ bias, unsigned char* __restrict__ m8,
    int nrows) {
  const int lane = threadIdx.x & 63;
  const int wv = threadIdx.x >> 6;
  const int r = lane & 15;
  const int kg = lane >> 4;

  const int row0 = blockIdx.x * 64 + wv * 16;
  if (row0 >= nrows) return;  // nrows % 16 == 0

  bf16x8 Bf[8][4];
#pragma unroll
  for (int n = 0; n < 8; ++n)
#pragma unroll
    for (int ks = 0; ks < 4; ++ks)
      Bf[n][ks] = *reinterpret_cast<const bf16x8*>(
          Wbf + (size_t)(n * 16 + r) * HN + ks * 32 + kg * 8);

  f32x4 acc[8];
#pragma unroll
  for (int n = 0; n < 8; ++n) {
    const float bv = bias[n * 16 + r];
    acc[n] = (f32x4){bv, bv, bv, bv};
  }

  bf16x8 Af[4];
  const float* xr = x + (size_t)(row0 + r) * HN + kg * 8;
#pragma unroll
  for (int ks = 0; ks < 4; ++ks) {
    const float4 f0 = *reinterpret_cast<const float4*>(xr + ks * 32);
    const float4 f1 = *reinterpret_cast<const float4*>(xr + ks * 32 + 4);
    bf16x8 a;
    a[0] = f2bs(f0.x); a[1] = f2bs(f0.y); a[2] = f2bs(f0.z); a[3] = f2bs(f0.w);
    a[4] = f2bs(f1.x); a[5] = f2bs(f1.y); a[6] = f2bs(f1.z); a[7] = f2bs(f1.w);
    Af[ks] = a;
  }

#pragma unroll
  for (int ks = 0; ks < 4; ++ks)
#pragma unroll
    for (int n = 0; n < 8; ++n)
      acc[n] = __builtin_amdgcn_mfma_f32_16x16x32_bf16(Af[ks], Bf[n][ks],
                                                       acc[n], 0, 0, 0);

#pragma unroll
  for (int n = 0; n < 8; ++n) {
#pragma unroll
    for (int reg = 0; reg < 4; ++reg) {
      const int rr = row0 + kg * 4 + reg;
      m8[(size_t)rr * HN + n * 16 + r] = f2fp8(fmaxf(acc[n][reg], 0.f));
    }
  }
}

// ---------------- degree histogram ----------------
__global__ void degree_k(const int* __restrict__ rows, int* __restrict__ deg,
                         int nedges) {
  for (int e = blockIdx.x * blockDim.x + threadIdx.x; e < nedges;
       e += gridDim.x * blockDim.x)
    atomicAdd(&deg[rows[e]], 1);
}

// ---------------- two-level scan ----------------
__global__ __launch_bounds__(SCHUNK) void blocksum_k(const int* __restrict__ deg,
                                                     int* __restrict__ bsum,
                                                     int n) {
  __shared__ int s[SCHUNK];
  const int i = blockIdx.x * SCHUNK + threadIdx.x;
  int v = (i < n) ? deg[i] : 0;
  s[threadIdx.x] = v;
  __syncthreads();
  for (int off = SCHUNK / 2; off > 0; off >>= 1) {
    if (threadIdx.x < off) s[threadIdx.x] += s[threadIdx.x + off];
    __syncthreads();
  }
  if (threadIdx.x == 0) bsum[blockIdx.x] = s[0];
}

__global__ __launch_bounds__(1024) void scan_bsums_k(int* __restrict__ bsum,
                                                     int* __restrict__ rowptr,
                                                     int nb, int n) {
  __shared__ int s[1024];
  const int t = threadIdx.x;
  int v = (t < nb) ? bsum[t] : 0;
  s[t] = v;
  __syncthreads();
  for (int off = 1; off < 1024; off <<= 1) {
    int u = 0;
    if (t >= off) u = s[t - off];
    __syncthreads();
    if (t >= off) s[t] += u;
    __syncthreads();
  }
  if (t < nb) bsum[t] = (t == 0) ? 0 : s[t - 1];
  if (t == 0) rowptr[n] = s[1023];
}

__global__ __launch_bounds__(SCHUNK) void rowptr_k(const int* __restrict__ deg,
                                                   const int* __restrict__ bsum,
                                                   int* __restrict__ rowptr,
                                                   int* __restrict__ cursor,
                                                   int n) {
  __shared__ int s[SCHUNK];
  const int i = blockIdx.x * SCHUNK + threadIdx.x;
  const int t = threadIdx.x;
  int v = (i < n) ? deg[i] : 0;
  s[t] = v;
  __syncthreads();
  for (int off = 1; off < SCHUNK; off <<= 1) {
    int u = 0;
    if (t >= off) u = s[t - off];
    __syncthreads();
    if (t >= off) s[t] += u;
    __syncthreads();
  }
  if (i < n) {
    const int excl = bsum[blockIdx.x] + s[t] - v;
    rowptr[i] = excl;
    cursor[i] = excl;
  }
}

// ---------------- row-sliced CSR fill, (slice, subrange) grid -------------
__global__ __launch_bounds__(1024) void fills_k(
    const int* __restrict__ rows, const int* __restrict__ cols,
    int* __restrict__ cursor, int* __restrict__ csr, int n, int nedges,
    int ch) {
  const int s = blockIdx.x & (NSLC - 1);
  const int sub = blockIdx.x / NSLC;
  const int lo = s * ch;
  const int hi = min(lo + ch, n);
  const int chunk = ((nedges + NSUB - 1) / NSUB + 3) & ~3;
  const int e0 = sub * chunk;
  const int e1 = min(e0 + chunk, nedges);
  if (e0 >= e1) return;

  const int4* rows4 = reinterpret_cast<const int4*>(rows + e0);
  const int4* cols4 = reinterpret_cast<const int4*>(cols + e0);
  const int nE = e1 - e0;
  const int ne4 = nE >> 2;
  for (int i = threadIdx.x; i < ne4; i += 1024) {
    const int4 rv = rows4[i];
    const int4 cv = cols4[i];
    if (rv.x >= lo && rv.x < hi) csr[atomicAdd(&cursor[rv.x], 1)] = cv.x;
    if (rv.y >= lo && rv.y < hi) csr[atomicAdd(&cursor[rv.y], 1)] = cv.y;
    if (rv.z >= lo && rv.z < hi) csr[atomicAdd(&cursor[rv.z], 1)] = cv.z;
    if (rv.w >= lo && rv.w < hi) csr[atomicAdd(&cursor[rv.w], 1)] = cv.w;
  }
  for (int e = e0 + (ne4 << 2) + threadIdx.x; e < e1; e += 1024) {
    const int r = rows[e];
    if (r >= lo && r < hi) csr[atomicAdd(&cursor[r], 1)] = cols[e];
  }
}

// ---------------- gather + avg + residual + RMSNorm (fused) ----------------
// One wave per row; QUARTER-wave (16 lanes) per edge, lane owns 8 cols
// (uint2 = 8B of fp8). One load inst covers 4 edges (512 B). Packed
// cvt_pk_f32_fp8 converts 2 values/inst. 32-bit index into m (dwordx2 with
// SGPR base) kills 64-bit addr math.
__global__ __launch_bounds__(256) void gather_k(
    const uint2* __restrict__ m2v, const int* __restrict__ rowptr,
    const int* __restrict__ csr, const float* __restrict__ x,
    const float* __restrict__ gamma, const float* __restrict__ beta,
    float* __restrict__ out, int nrows) {
  const int r = blockIdx.x * 4 + (threadIdx.x >> 6);
  if (r >= nrows) return;
  const int lane = threadIdx.x & 63;
  const int q = lane >> 4;   // quarter id: which edge of the group of 4
  const int l = lane & 15;   // position within quarter: col octet

  const int start = rowptr[r];
  const int end = rowptr[r + 1];
  float a[8] = {0.f, 0.f, 0.f, 0.f, 0.f, 0.f, 0.f, 0.f};

  for (int base = start; base < end; base += 64) {
    const int nv = min(64, end - base);
    const int c = (base + lane < end) ? csr[base + lane] : 0;
    for (int j = 0; j < nv; j += 4) {
      const int cc = __shfl(c, j + q);
      if (j + q < nv) {
        const uint2 u = m2v[cc * 16 + l];  // 32-bit index
#if __has_builtin(__builtin_amdgcn_cvt_pk_f32_fp8)
        const f32x2 f0 = __builtin_amdgcn_cvt_pk_f32_fp8(u.x, 0);
        const f32x2 f1 = __builtin_amdgcn_cvt_pk_f32_fp8(u.x, 1);
        const f32x2 f2 = __builtin_amdgcn_cvt_pk_f32_fp8(u.y, 0);
        const f32x2 f3 = __builtin_amdgcn_cvt_pk_f32_fp8(u.y, 1);
        a[0] += f0.x; a[1] += f0.y; a[2] += f1.x; a[3] += f1.y;
        a[4] += f2.x; a[5] += f2.y; a[6] += f3.x; a[7] += f3.y;
#else
        a[0] += __builtin_amdgcn_cvt_f32_fp8(u.x, 0);
        a[1] += __builtin_amdgcn_cvt_f32_fp8(u.x, 1);
        a[2] += __builtin_amdgcn_cvt_f32_fp8(u.x, 2);
        a[3] += __builtin_amdgcn_cvt_f32_fp8(u.x, 3);
        a[4] += __builtin_amdgcn_cvt_f32_fp8(u.y, 0);
        a[5] += __builtin_amdgcn_cvt_f32_fp8(u.y, 1);
        a[6] += __builtin_amdgcn_cvt_f32_fp8(u.y, 2);
        a[7] += __builtin_amdgcn_cvt_f32_fp8(u.y, 3);
#endif
      }
    }
  }

  // combine the 4 quarters (lanes {l, l+16, l+32, l+48} hold same cols)
#pragma unroll
  for (int i = 0; i < 8; ++i) {
    a[i] += __shfl_xor(a[i], 16);
    a[i] += __shfl_xor(a[i], 32);
  }

  const int d = end - start;
  const float inv_d = (d > 0) ? 1.f / (float)d : 1.f;
  const float4 xv0 = *reinterpret_cast<const float4*>(x + (size_t)r * HN + 8 * l);
  const float4 xv1 = *reinterpret_cast<const float4*>(x + (size_t)r * HN + 8 * l + 4);
  float h[8];
  h[0] = xv0.x + a[0] * inv_d; h[1] = xv0.y + a[1] * inv_d;
  h[2] = xv0.z + a[2] * inv_d; h[3] = xv0.w + a[3] * inv_d;
  h[4] = xv1.x + a[4] * inv_d; h[5] = xv1.y + a[5] * inv_d;
  h[6] = xv1.z + a[6] * inv_d; h[7] = xv1.w + a[7] * inv_d;

  float ss = 0.f;
#pragma unroll
  for (int i = 0; i < 8; ++i) ss += h[i] * h[i];
  // each 16-lane group spans all 128 cols -> reduce within group only
  ss += __shfl_xor(ss, 1);
  ss += __shfl_xor(ss, 2);
  ss += __shfl_xor(ss, 4);
  ss += __shfl_xor(ss, 8);
  const float invrms = rsqrtf(ss * (1.f / HN) + EPS);

  if (q == 0) {
    const float4 gv0 = *reinterpret_cast<const float4*>(gamma + 8 * l);
    const float4 gv1 = *reinterpret_cast<const float4*>(gamma + 8 * l + 4);
    const float4 bv0 = *reinterpret_cast<const float4*>(beta + 8 * l);
    const float4 bv1 = *reinterpret_cast<const float4*>(beta + 8 * l + 4);
    float4 o0, o1;
    o0.x = h[0] * invrms * gv0.x + bv0.x;
    o0.y = h[1] * invrms * gv0.y + bv0.y;
    o0.z = h[2] * invrms * gv0.z + bv0.z;
    o0.w = h[3] * invrms * gv0.w + bv0.w;
    o1.x = h[4] * invrms * gv1.x + bv1.x;
    o1.y = h[5] * invrms * gv1.y + bv1.y;
    o1.z = h[6] * invrms * gv1.z + bv1.z;
    o1.w = h[7] * invrms * gv1.w + bv1.w;
    *reinterpret_cast<float4*>(out + (size_t)r * HN + 8 * l) = o0;
    *reinterpret_cast<float4*>(out + (size_t)r * HN + 8 * l + 4) = o1;
  }
}

extern "C" void kernel_launch(void* const* d_in, const int* in_sizes, int n_in,
                              void* d_out, int out_size, void* d_ws,
                              size_t ws_size, hipStream_t stream) {
  const float* x = (const float*)d_in[0];
  const float* W = (const float*)d_in[1];
  const float* b = (const float*)d_in[2];
  const float* gamma = (const float*)d_in[3];
  const float* beta = (const float*)d_in[4];
  const int* rows = (const int*)d_in[5];
  const int* cols = (const int*)d_in[6];
  float* out = (float*)d_out;

  const int N = in_sizes[0] / HN;  // 100000
  const int E = in_sizes[5];       // 1600000

  // ws layout: m_fp8 | Wbf | deg | rowptr | cursor | bsum | csr
  char* p = (char*)d_ws;
  unsigned char* m8 = (unsigned char*)p;
  p += ((size_t)N * HN + 255) & ~(size_t)255;
  __hip_bfloat16* Wbf = (__hip_bfloat16*)p;
  p += ((size_t)HN * HN * sizeof(__hip_bfloat16) + 255) & ~(size_t)255;
  int* deg = (int*)p;
  p += ((size_t)N * sizeof(int) + 255) & ~(size_t)255;
  int* rowptr = (int*)p;
  p += ((size_t)(N + 1) * sizeof(int) + 255) & ~(size_t)255;
  int* cursor = (int*)p;
  p += ((size_t)N * sizeof(int) + 255) & ~(size_t)255;
  int* bsum = (int*)p;
  p += ((size_t)2048 * sizeof(int) + 255) & ~(size_t)255;
  int* csr = (int*)p;

  hipMemsetAsync(deg, 0, (size_t)N * sizeof(int), stream);

  const int nb = (N + SCHUNK - 1) / SCHUNK;  // 391
  const int ch = (N + NSLC - 1) / NSLC;      // 12500

  wconv_k<<<(HN * HN + 255) / 256, 256, 0, stream>>>(W, Wbf);
  gemm_mfma_k<<<(N + 63) / 64, 256, 0, stream>>>(x, Wbf, b, m8, N);
  degree_k<<<1024, 256, 0, stream>>>(rows, deg, E);
  blocksum_k<<<nb, SCHUNK, 0, stream>>>(deg, bsum, N);
  scan_bsums_k<<<1, 1024, 0, stream>>>(bsum, rowptr, nb, N);
  rowptr_k<<<nb, SCHUNK, 0, stream>>>(deg, bsum, rowptr, cursor, N);
  fills_k<<<NSLC * NSUB, 1024, 0, stream>>>(rows, cols, cursor, csr, N, E, ch);
  gather_k<<<(N + 3) / 4, 256, 0, stream>>>((const uint2*)m8, rowptr, csr, x,
                                            gamma, beta, out, N);
}